// Round 7
// baseline (5443.914 us; speedup 1.0000x reference)
//
#include <hip/hip_runtime.h>
#include <cstdint>

typedef short short8  __attribute__((ext_vector_type(8)));
typedef unsigned short ushort4v __attribute__((ext_vector_type(4)));
typedef float floatx4 __attribute__((ext_vector_type(4)));

#define HID    128
#define NB     64
#define TPB    512
#define NBLK   1024          // 65536 / 64
#define TSTEPS 30
#define MU_OFF 5898240       // 65536*30*3

// ws layout (bf16 units): A-fragment-swizzled weight arrays, hi then lo per set
#define L0_SZ  81920         // 512*160  (K-ext: [Whh(128)|Wih0(3)|0(29)])
#define L1_SZ  131072        // 512*256  (K-ext: [Wih1(128)|Whh1(128)])
#define ENC0_HI 0
#define ENC0_LO 81920
#define ENC1_HI 163840
#define ENC1_LO 294912
#define DEC0_HI 425984
#define DEC0_LO 507904
#define DEC1_HI 589824
#define DEC1_LO 720896

#define S0 128               // h0 row stride (bf16): 16 k-blocks
#define S1 128               // h1 row stride: 16 k-blocks

// v_rcp_f32 (~1 ulp) instead of the IEEE div chain
__device__ __forceinline__ float sigm(float v){
  return __builtin_amdgcn_rcpf(1.f + __expf(-v));
}
__device__ __forceinline__ float tanh_fast(float v){
  return 2.f*__builtin_amdgcn_rcpf(1.f + __expf(-2.f*v)) - 1.f;
}

__device__ __forceinline__ unsigned short f2bf(float f){
  unsigned u = __float_as_uint(f);
  u = (u + 0x7FFF + ((u>>16)&1)) >> 16;     // RNE; inputs finite
  return (unsigned short)u;
}
__device__ __forceinline__ float bf2f(unsigned short b){
  return __uint_as_float(((unsigned)b)<<16);
}

// ---------------- prep: swizzle weights into A-fragment order, bf16 hi/lo ----
// A-frag element (mt, kt, lane l, jj):  A[mt*16 + (l&15)][kt*32 + ((l>>4)&3)*8 + jj]
// stored at ((mt*KT + kt)*64 + l)*8 + jj   -> consumer does 1 coalesced b128/lane
extern "C" __global__ void __launch_bounds__(256)
prep_frag(const float* __restrict__ eWih0, const float* __restrict__ eWhh0,
          const float* __restrict__ eWih1, const float* __restrict__ eWhh1,
          const float* __restrict__ dWih0, const float* __restrict__ dWhh0,
          const float* __restrict__ dWih1, const float* __restrict__ dWhh1,
          unsigned short* __restrict__ ws)
{
  const int idx = blockIdx.x*256 + threadIdx.x;   // one thread -> one (hi,lo) pair
  int i2, hi_base, lo_base, KT;
  const float* Wa; const float* Wb;
  if (idx < L0_SZ)                { i2=idx;                 hi_base=ENC0_HI; lo_base=ENC0_LO; Wa=eWhh0; Wb=eWih0; KT=5; }
  else if (idx < L0_SZ+L1_SZ)     { i2=idx-L0_SZ;           hi_base=ENC1_HI; lo_base=ENC1_LO; Wa=eWih1; Wb=eWhh1; KT=8; }
  else if (idx < 2*L0_SZ+L1_SZ)   { i2=idx-(L0_SZ+L1_SZ);   hi_base=DEC0_HI; lo_base=DEC0_LO; Wa=dWhh0; Wb=dWih0; KT=5; }
  else                            { i2=idx-(2*L0_SZ+L1_SZ); hi_base=DEC1_HI; lo_base=DEC1_LO; Wa=dWih1; Wb=dWhh1; KT=8; }
  const int jj = i2 & 7, l = (i2>>3)&63, tk = i2>>9;
  const int kt = (KT==5) ? (tk%5) : (tk&7);
  const int mt = (KT==5) ? (tk/5) : (tk>>3);
  const int row = mt*16 + (l&15);
  const int k   = kt*32 + ((l>>4)&3)*8 + jj;
  float w;
  if (KT==5) w = (k<128) ? Wa[row*128+k] : ((k<131) ? Wb[row*3 + (k-128)] : 0.f);
  else       w = (k<128) ? Wa[row*128+k] : Wb[row*128 + (k-128)];
  const unsigned short hi = f2bf(w);
  ws[hi_base + i2] = hi;
  ws[lo_base + i2] = f2bf(w - bf2f(hi));
}

// ------- fused LSTM: NB=64/block, two anti-phase wave-halves ----------------
// half = w>>2 (waves 0-3: batch rows 0-31; waves 4-7: rows 32-63).
// Round-robin wave->SIMD placement puts one wave of each half on every SIMD;
// half B runs one sub-phase behind half A, so each barrier interval pairs one
// half's MFMA phase with the other half's VALU phase (m114 co-issue).
// Within a half, wave w2=w&3 owns m-tiles mt = g*8 + w2*2 + s (j in [32w2,32w2+32))
extern "C" __global__ void __launch_bounds__(TPB, 2)
lstm_mfma(const float* __restrict__ x,
          const unsigned short* __restrict__ wf,
          const float* __restrict__ enc_b0, const float* __restrict__ enc_b1,
          const float* __restrict__ dec_b0, const float* __restrict__ dec_b1,
          const float* __restrict__ fc_W,  const float* __restrict__ fc_b,
          float* __restrict__ out)
{
  // h in B-frag layout: element (n,k) at n*S + ((k>>3)^(n&7))*8 + (k&7)
  __shared__ unsigned short h0h[NB*S0], h0l[NB*S0];
  __shared__ unsigned short h1h[NB*S1], h1l[NB*S1];
  __shared__ unsigned short xbh[NB*8],  xbl[NB*8];   // x / mu feedback, unswizzled
  __shared__ unsigned short fcAh[4*512], fcAl[4*512];// FC weights, A-frag layout
  __shared__ float bias[2048];                        // [enc0|enc1|dec0|dec1]

  const int tid  = threadIdx.x;
  const int w    = tid>>6, l = tid&63;
  const int half = w>>2, w2 = w&3;
  const int rb   = half*32;                           // batch-row base of my half
  const int quad = (l>>4)&3, n15 = l&15, q7 = n15&7;
  const int b0   = blockIdx.x*NB;

  bias[tid]      = enc_b0[tid];
  bias[512+tid]  = enc_b1[tid];
  bias[1024+tid] = dec_b0[tid];
  bias[1536+tid] = dec_b1[tid];
  for (int i=tid;i<NB*S0;i+=TPB){ h0h[i]=0; h0l[i]=0; h1h[i]=0; h1l[i]=0; }
  xbh[tid]=0; xbl[tid]=0;                    // NB*8 == 512 == TPB
  // FC weights -> LDS A-frags (wave w<4 stages kt=w)
  if (w < 4){
    short8 vh, vl;
#pragma unroll
    for (int jj=0;jj<8;jj++){
      const float f = (n15<6) ? fc_W[n15*HID + w*32 + quad*8 + jj] : 0.f;
      const unsigned short hi = f2bf(f);
      vh[jj] = (short)hi;
      vl[jj] = (short)f2bf(f - bf2f(hi));
    }
    *(short8*)(fcAh + (w*64+l)*8) = vh;
    *(short8*)(fcAl + (w*64+l)*8) = vl;
  }
  float myfcb[4];
#pragma unroll
  for (int r=0;r<4;r++){
    const int oi = quad*4 + r;
    myfcb[r] = (oi<6) ? fc_b[oi] : 0.f;
  }
  __syncthreads();

  auto write_x = [&](int t){
    if (tid < 192){
      const int n = tid & 63, c = tid >> 6;
      const float v = x[(size_t)(b0+n)*90 + t*3 + c];
      const unsigned short hi = f2bf(v);
      xbh[n*8+c] = hi; xbl[n*8+c] = f2bf(v - bf2f(hi));
    }
  };
  write_x(0);
  __syncthreads();

  floatx4 acc[8][2];                 // [p=g*2+s][nt]; single set, reused per phase
  float c0[2][2][4], c1[2][2][4];    // [s][nt][r]
#pragma unroll
  for (int s=0;s<2;s++)
#pragma unroll
    for (int nt=0;nt<2;nt++)
#pragma unroll
      for (int r=0;r<4;r++){ c0[s][nt][r]=0.f; c1[s][nt][r]=0.f; }

  auto zacc = [&]{
    const floatx4 z = {0.f,0.f,0.f,0.f};
#pragma unroll
    for (int p=0;p<8;p++){ acc[p][0]=z; acc[p][1]=z; }
  };

  // acc += A(kt range) * B.  Combo-major MFMA order: 8 independent accs
  // between same-acc reuses. Per-acc add order hh->hl->lh per kt preserved.
  auto mv = [&](const unsigned short* __restrict__ Ahi,
                const unsigned short* __restrict__ Alo, int KT,
                int k0, int k1, int kboff,
                const unsigned short* Bh, const unsigned short* Bl, int SS){
#pragma unroll 1
    for (int kt=k0; kt<k1; ++kt){
      const int bo = ((((kt-kboff)*4+quad)^q7)<<3);
      short8 bh[2], bl[2];
#pragma unroll
      for (int nt=0;nt<2;nt++){
        const int ro = (rb + nt*16 + n15)*SS + bo;
        bh[nt] = *(const short8*)(Bh + ro);
        bl[nt] = *(const short8*)(Bl + ro);
      }
#pragma unroll
      for (int gp=0;gp<2;gp++){
        short8 ah[4], al[4];
#pragma unroll
        for (int i=0;i<4;i++){
          const int g = gp*2 + (i>>1), s = i&1;
          const int mt = g*8 + w2*2 + s;
          const int ao = ((mt*KT + kt)*64 + l)*8;
          ah[i] = *(const short8*)(Ahi + ao);
          al[i] = *(const short8*)(Alo + ao);
        }
#pragma unroll
        for (int i=0;i<4;i++){
          acc[gp*4+i][0] = __builtin_amdgcn_mfma_f32_16x16x32_bf16(ah[i], bh[0], acc[gp*4+i][0],0,0,0);
          acc[gp*4+i][1] = __builtin_amdgcn_mfma_f32_16x16x32_bf16(ah[i], bh[1], acc[gp*4+i][1],0,0,0);
        }
#pragma unroll
        for (int i=0;i<4;i++){
          acc[gp*4+i][0] = __builtin_amdgcn_mfma_f32_16x16x32_bf16(ah[i], bl[0], acc[gp*4+i][0],0,0,0);
          acc[gp*4+i][1] = __builtin_amdgcn_mfma_f32_16x16x32_bf16(ah[i], bl[1], acc[gp*4+i][1],0,0,0);
        }
#pragma unroll
        for (int i=0;i<4;i++){
          acc[gp*4+i][0] = __builtin_amdgcn_mfma_f32_16x16x32_bf16(al[i], bh[0], acc[gp*4+i][0],0,0,0);
          acc[gp*4+i][1] = __builtin_amdgcn_mfma_f32_16x16x32_bf16(al[i], bh[1], acc[gp*4+i][1],0,0,0);
        }
      }
    }
  };

  // kt=4 of layer 0: B comes from xbuf (k=128..135; real data k<131, quad 0 only)
  auto mv_x = [&](const unsigned short* __restrict__ Ahi,
                  const unsigned short* __restrict__ Alo){
    const short8 z8 = {0,0,0,0,0,0,0,0};
    short8 bh[2]={z8,z8}, bl[2]={z8,z8};
    if (quad==0){
#pragma unroll
      for (int nt=0;nt<2;nt++){
        const int ro = (rb + nt*16 + n15)*8;
        bh[nt] = *(const short8*)(xbh + ro);
        bl[nt] = *(const short8*)(xbl + ro);
      }
    }
#pragma unroll
    for (int gp=0;gp<2;gp++){
      short8 ah[4], al[4];
#pragma unroll
      for (int i=0;i<4;i++){
        const int g = gp*2 + (i>>1), s = i&1;
        const int mt = g*8 + w2*2 + s;
        const int ao = ((mt*5 + 4)*64 + l)*8;
        ah[i] = *(const short8*)(Ahi + ao);
        al[i] = *(const short8*)(Alo + ao);
      }
#pragma unroll
      for (int i=0;i<4;i++){
        acc[gp*4+i][0] = __builtin_amdgcn_mfma_f32_16x16x32_bf16(ah[i], bh[0], acc[gp*4+i][0],0,0,0);
        acc[gp*4+i][1] = __builtin_amdgcn_mfma_f32_16x16x32_bf16(ah[i], bh[1], acc[gp*4+i][1],0,0,0);
      }
#pragma unroll
      for (int i=0;i<4;i++){
        acc[gp*4+i][0] = __builtin_amdgcn_mfma_f32_16x16x32_bf16(ah[i], bl[0], acc[gp*4+i][0],0,0,0);
        acc[gp*4+i][1] = __builtin_amdgcn_mfma_f32_16x16x32_bf16(ah[i], bl[1], acc[gp*4+i][1],0,0,0);
      }
#pragma unroll
      for (int i=0;i<4;i++){
        acc[gp*4+i][0] = __builtin_amdgcn_mfma_f32_16x16x32_bf16(al[i], bh[0], acc[gp*4+i][0],0,0,0);
        acc[gp*4+i][1] = __builtin_amdgcn_mfma_f32_16x16x32_bf16(al[i], bh[1], acc[gp*4+i][1],0,0,0);
      }
    }
  };

  // gates -> c -> h -> bf16 hi/lo pack -> LDS h write (no internal barrier:
  // interval barriers order all cross-wave reads/writes; halves' rows disjoint)
  auto act_hwr = [&](float (&cst)[2][2][4], int boff,
                     unsigned short* Hh, unsigned short* Hl, int SS){
#pragma unroll
    for (int s=0;s<2;s++)
#pragma unroll
      for (int nt=0;nt<2;nt++){
        ushort4v ph, pl;
#pragma unroll
        for (int r=0;r<4;r++){
          const int j = (w2*2+s)*16 + quad*4 + r;
          const float i_ = sigm(acc[0+s][nt][r]      + bias[boff       + j]);
          const float f_ = sigm(acc[2+s][nt][r]      + bias[boff + 128 + j]);
          const float g_ = tanh_fast(acc[4+s][nt][r] + bias[boff + 256 + j]);
          const float o_ = sigm(acc[6+s][nt][r]      + bias[boff + 384 + j]);
          const float c  = f_*cst[s][nt][r] + i_*g_;
          cst[s][nt][r] = c;
          const float h  = o_*tanh_fast(c);
          const unsigned short hi = f2bf(h);
          ph[r] = hi;
          pl[r] = f2bf(h - bf2f(hi));
        }
        const int jb = (w2*2+s)*2 + (quad>>1);       // j>>3
        const int n  = rb + nt*16 + n15;
        const int base = n*SS + ((jb ^ (n&7))<<3) + ((quad&1)<<2);
        *(ushort4v*)(Hh + base) = ph;                // ds_write_b64
        *(ushort4v*)(Hl + base) = pl;
      }
  };

  // FC head via MFMA on h1 rows of my half (waves w2<2, 16 rows each)
  auto fc = [&](int t){
    if (w2 < 2){
      floatx4 fa = {0.f,0.f,0.f,0.f};
#pragma unroll
      for (int kt=0;kt<4;kt++){
        const short8 ah = *(const short8*)(fcAh + (kt*64+l)*8);
        const short8 al = *(const short8*)(fcAl + (kt*64+l)*8);
        const int bo = (((kt*4+quad)^q7)<<3);
        const int ro = (rb + w2*16 + n15)*S1 + bo;
        const short8 bh = *(const short8*)(h1h + ro);
        const short8 bl = *(const short8*)(h1l + ro);
        fa = __builtin_amdgcn_mfma_f32_16x16x32_bf16(ah, bh, fa,0,0,0);
        fa = __builtin_amdgcn_mfma_f32_16x16x32_bf16(ah, bl, fa,0,0,0);
        fa = __builtin_amdgcn_mfma_f32_16x16x32_bf16(al, bh, fa,0,0,0);
      }
      const int n = rb + w2*16 + n15;
      const size_t off = (size_t)(b0+n)*90 + (size_t)t*3;
      if (quad == 0){
#pragma unroll
        for (int r=0;r<4;r++){
          const float s = fa[r] + myfcb[r];
          if (r < 3){
            out[off + r] = s;                        // mu
            const unsigned short hi = f2bf(s);       // feed mu back as next x
            xbh[n*8+r] = hi; xbl[n*8+r] = f2bf(s - bf2f(hi));
          } else {
            out[MU_OFF + off] = s;                   // logvar[0]
          }
        }
      } else if (quad == 1){
#pragma unroll
        for (int r=0;r<2;r++)
          out[MU_OFF + off + 1 + r] = fa[r] + myfcb[r];  // logvar[1,2]
      }
    }
  };

  // ---------------- encoder: anti-phase halves, 4 intervals/step ----------
  // A: P1(t)@I1  A1(t)@I2  P2(t)@I3  A2(t)@I4
  // B: A2(t-1)@I1  P1(t)@I2  A1(t)@I3  P2(t)@I4
#pragma unroll 1
  for (int t=0; t<TSTEPS; ++t){
    // I1
    if (half==0){
      zacc();
      mv  (wf+ENC0_HI, wf+ENC0_LO, 5, 0, 4, 0, h0h, h0l, S0);
      mv_x(wf+ENC0_HI, wf+ENC0_LO);
    } else if (t > 0){
      act_hwr(c1, 512, h1h, h1l, S1);
    }
    __syncthreads();
    // I2
    if (half==0){
      act_hwr(c0, 0, h0h, h0l, S0);
    } else {
      zacc();
      mv  (wf+ENC0_HI, wf+ENC0_LO, 5, 0, 4, 0, h0h, h0l, S0);
      mv_x(wf+ENC0_HI, wf+ENC0_LO);
    }
    __syncthreads();
    // I3
    if (half==0){
      zacc();                                        // <-- R5 bug fix
      mv(wf+ENC1_HI, wf+ENC1_LO, 8, 4, 8, 4, h1h, h1l, S1);
      mv(wf+ENC1_HI, wf+ENC1_LO, 8, 0, 4, 0, h0h, h0l, S0);
    } else {
      act_hwr(c0, 0, h0h, h0l, S0);
    }
    if (t+1 < TSTEPS) write_x(t+1);      // half-A waves; xbuf read next at I1/I2 of t+1
    __syncthreads();
    // I4
    if (half==0){
      act_hwr(c1, 512, h1h, h1l, S1);
    } else {
      zacc();                                        // <-- R5 bug fix
      mv(wf+ENC1_HI, wf+ENC1_LO, 8, 4, 8, 4, h1h, h1l, S1);
      mv(wf+ENC1_HI, wf+ENC1_LO, 8, 0, 4, 0, h0h, h0l, S0);
    }
    __syncthreads();
  }
  // B still owes enc A2(29)
  if (half==1) act_hwr(c1, 512, h1h, h1l, S1);
  __syncthreads();
  // xbuf still holds x[:,29,:] == decoder's initial input

  // ---------------- decoder: 5 intervals/step ------------------------------
  // A: P1(t)@I1  A1(t)@I2  P2(t)@I3  A2(t)@I4  FC(t)@I5
  // B: A2(t-1)@I1  FC(t-1)@I2  P1(t)@I3  A1(t)@I4  P2(t)@I5
#pragma unroll 1
  for (int t=0; t<TSTEPS; ++t){
    // I1
    if (half==0){
      zacc();
      mv  (wf+DEC0_HI, wf+DEC0_LO, 5, 0, 4, 0, h0h, h0l, S0);
      mv_x(wf+DEC0_HI, wf+DEC0_LO);
    } else if (t > 0){
      act_hwr(c1, 1536, h1h, h1l, S1);
    }
    __syncthreads();
    // I2
    if (half==0){
      act_hwr(c0, 1024, h0h, h0l, S0);
    } else if (t > 0){
      fc(t-1);
    }
    __syncthreads();
    // I3
    if (half==0){
      zacc();                                        // <-- R5 bug fix
      mv(wf+DEC1_HI, wf+DEC1_LO, 8, 4, 8, 4, h1h, h1l, S1);
      mv(wf+DEC1_HI, wf+DEC1_LO, 8, 0, 4, 0, h0h, h0l, S0);
    } else {
      zacc();
      mv  (wf+DEC0_HI, wf+DEC0_LO, 5, 0, 4, 0, h0h, h0l, S0);
      mv_x(wf+DEC0_HI, wf+DEC0_LO);
    }
    __syncthreads();
    // I4
    if (half==0){
      act_hwr(c1, 1536, h1h, h1l, S1);
    } else {
      act_hwr(c0, 1024, h0h, h0l, S0);
    }
    __syncthreads();
    // I5
    if (half==0){
      fc(t);
    } else {
      zacc();                                        // <-- R5 bug fix
      mv(wf+DEC1_HI, wf+DEC1_LO, 8, 4, 8, 4, h1h, h1l, S1);
      mv(wf+DEC1_HI, wf+DEC1_LO, 8, 0, 4, 0, h0h, h0l, S0);
    }
    __syncthreads();
  }
  // epilogue: B owes A2(29) then FC(29)
  if (half==1) act_hwr(c1, 1536, h1h, h1l, S1);
  __syncthreads();
  if (half==1) fc(TSTEPS-1);
}

extern "C" void kernel_launch(void* const* d_in, const int* in_sizes, int n_in,
                              void* d_out, int out_size, void* d_ws, size_t ws_size,
                              hipStream_t stream) {
  const float* x        = (const float*)d_in[0];
  const float* enc_Wih0 = (const float*)d_in[1];
  const float* enc_Whh0 = (const float*)d_in[2];
  const float* enc_b0   = (const float*)d_in[3];
  const float* enc_Wih1 = (const float*)d_in[4];
  const float* enc_Whh1 = (const float*)d_in[5];
  const float* enc_b1   = (const float*)d_in[6];
  const float* dec_Wih0 = (const float*)d_in[7];
  const float* dec_Whh0 = (const float*)d_in[8];
  const float* dec_b0   = (const float*)d_in[9];
  const float* dec_Wih1 = (const float*)d_in[10];
  const float* dec_Whh1 = (const float*)d_in[11];
  const float* dec_b1   = (const float*)d_in[12];
  const float* fc_W     = (const float*)d_in[13];
  const float* fc_b     = (const float*)d_in[14];
  unsigned short* ws = (unsigned short*)d_ws;
  float* out = (float*)d_out;

  // 425,984 (hi,lo) pairs -> exactly 1664 blocks of 256
  prep_frag<<<1664, 256, 0, stream>>>(
      enc_Wih0, enc_Whh0, enc_Wih1, enc_Whh1,
      dec_Wih0, dec_Whh0, dec_Wih1, dec_Whh1, ws);

  lstm_mfma<<<NBLK, TPB, 0, stream>>>(
      x, ws, enc_b0, enc_b1, dec_b0, dec_b1, fc_W, fc_b, out);
}